// Round 2
// baseline (228.053 us; speedup 1.0000x reference)
//
#include <hip/hip_runtime.h>
#include <hip/hip_bf16.h>
#include <stdint.h>

#define NROWS 8192
#define NF    1024
#define EPSV  1e-5f

typedef __attribute__((ext_vector_type(8))) short bf16x8;
typedef __attribute__((ext_vector_type(4))) float f32x4;

// ---------------- Kernel 1: per-chunk column sums ----------------
__global__ void stats_partial(const float* __restrict__ X, const float* __restrict__ Y,
                              float* __restrict__ psum, float* __restrict__ psq) {
    int cg    = blockIdx.x;   // 0..3  column group of 256
    int chunk = blockIdx.y;   // 0..63 row chunk of 128
    int mat   = blockIdx.z;   // 0..1
    const float* A = mat ? Y : X;
    int col = cg * 256 + threadIdx.x;
    const float* p = A + (size_t)(chunk * 128) * NF + col;
    float s = 0.f, sq = 0.f;
    #pragma unroll 4
    for (int i = 0; i < 128; ++i) {
        float v = p[(size_t)i * NF];
        s += v; sq += v * v;
    }
    int idx = (mat * 64 + chunk) * NF + col;
    psum[idx] = s;
    psq[idx]  = sq;
}

// ---------------- Kernel 2: finalize mu / inv_sd ----------------
__global__ void stats_final(const float* __restrict__ psum, const float* __restrict__ psq,
                            float* __restrict__ mu, float* __restrict__ isd) {
    int t = blockIdx.x * 256 + threadIdx.x;   // 0..2047
    int mat = t >> 10, col = t & 1023;
    float s = 0.f, sq = 0.f;
    for (int ch = 0; ch < 64; ++ch) {
        int idx = (mat * 64 + ch) * NF + col;
        s  += psum[idx];
        sq += psq[idx];
    }
    float m   = s / (float)NROWS;
    float var = (sq - s * m) / (float)(NROWS - 1);
    var = fmaxf(var, 0.f);
    mu[t]  = m;
    isd[t] = 1.0f / (sqrtf(var) + EPSV);
}

// ------- Kernel 3: standardize + bf16 cast + transpose to [col][k] -------
// tbuf padded to 72 elements/row: write-side bank conflict 16-way -> 8-way,
// read side stays 16B-aligned (144 % 16 == 0) for ds_read_b128.
__global__ void std_transpose(const float* __restrict__ X, const float* __restrict__ Y,
                              const float* __restrict__ mu, const float* __restrict__ isd,
                              __hip_bfloat16* __restrict__ Xst, __hip_bfloat16* __restrict__ Yst) {
    __shared__ __hip_bfloat16 tbuf[64][72];   // [col][row] within tile, padded
    __shared__ float smu[64], sisd[64];
    int ct  = blockIdx.x;    // 0..15  column tile
    int rt  = blockIdx.y;    // 0..127 row tile
    int mat = blockIdx.z;
    const float* A = mat ? Y : X;
    __hip_bfloat16* O = mat ? Yst : Xst;
    int tid = threadIdx.x;
    if (tid < 64) {
        smu[tid]  = mu [mat * NF + ct * 64 + tid];
        sisd[tid] = isd[mat * NF + ct * 64 + tid];
    }
    __syncthreads();
    #pragma unroll
    for (int it = 0; it < 4; ++it) {
        int idx = it * 256 + tid;     // 0..1023
        int row = idx >> 4;           // 0..63
        int c4  = idx & 15;           // 0..15
        float4 v = *reinterpret_cast<const float4*>(
            A + (size_t)(rt * 64 + row) * NF + ct * 64 + c4 * 4);
        float vs[4] = {v.x, v.y, v.z, v.w};
        #pragma unroll
        for (int j = 0; j < 4; ++j) {
            int c = c4 * 4 + j;
            tbuf[c][row] = __float2bfloat16((vs[j] - smu[c]) * sisd[c]);
        }
    }
    __syncthreads();
    #pragma unroll
    for (int it = 0; it < 2; ++it) {
        int idx = it * 256 + tid;     // 0..511
        int col = idx >> 3;           // 0..63
        int k8  = idx & 7;            // 0..7
        bf16x8 v = *reinterpret_cast<const bf16x8*>(&tbuf[col][k8 * 8]);
        *reinterpret_cast<bf16x8*>(O + (size_t)(ct * 64 + col) * NROWS + rt * 64 + k8 * 8) = v;
    }
}

// ------- Kernel 4: Gram GEMM, 128x128 tile, upper-tri, split-K=2 -------
__global__ __launch_bounds__(256, 2) void gram_gemm(
    const __hip_bfloat16* __restrict__ Xst, const __hip_bfloat16* __restrict__ Yst,
    float* __restrict__ Cpart) {
    __shared__ short As[128 * 32];
    __shared__ short Bs[128 * 32];
    int tile = blockIdx.x, split = blockIdx.y, mat = blockIdx.z;
    // upper-tri tile id -> (r, c), c >= r, 8x8 grid
    int r = 0, t = tile;
    while (t >= 8 - r) { t -= 8 - r; ++r; }
    int c = r + t;
    const short* A = reinterpret_cast<const short*>(mat ? Yst : Xst);
    int tid = threadIdx.x, lane = tid & 63, wid = tid >> 6;
    int wr = wid >> 1, wc = wid & 1;
    f32x4 acc[4][4] = {};
    int k0 = split * 4096;

    for (int step = 0; step < 128; ++step) {
        int kk = k0 + step * 32;
        __syncthreads();   // previous tile's compute done before overwrite
        #pragma unroll
        for (int i = 0; i < 2; ++i) {
            int chunk = wid * 2 + i;
            int m = chunk * 16 + (lane >> 2);
            const short* ga = A + (size_t)(r * 128 + m) * NROWS + kk + (lane & 3) * 8;
            __builtin_amdgcn_global_load_lds(
                (const __attribute__((address_space(1))) void*)ga,
                (__attribute__((address_space(3))) void*)(As + chunk * 512), 16, 0, 0);
            const short* gb = A + (size_t)(c * 128 + m) * NROWS + kk + (lane & 3) * 8;
            __builtin_amdgcn_global_load_lds(
                (const __attribute__((address_space(1))) void*)gb,
                (__attribute__((address_space(3))) void*)(Bs + chunk * 512), 16, 0, 0);
        }
        __syncthreads();   // loads complete (compiler drains vmcnt before barrier)
        bf16x8 af[4], bfr[4];
        #pragma unroll
        for (int fm = 0; fm < 4; ++fm) {
            af[fm]  = *reinterpret_cast<const bf16x8*>(
                &As[(wr * 64 + fm * 16 + (lane & 15)) * 32 + (lane >> 4) * 8]);
            bfr[fm] = *reinterpret_cast<const bf16x8*>(
                &Bs[(wc * 64 + fm * 16 + (lane & 15)) * 32 + (lane >> 4) * 8]);
        }
        #pragma unroll
        for (int fm = 0; fm < 4; ++fm)
            #pragma unroll
            for (int fn = 0; fn < 4; ++fn)
                acc[fm][fn] = __builtin_amdgcn_mfma_f32_16x16x32_bf16(
                    af[fm], bfr[fn], acc[fm][fn], 0, 0, 0);
    }

    float* Cp = Cpart + ((size_t)(mat * 2 + split) * 36 + tile) * 16384;
    #pragma unroll
    for (int fm = 0; fm < 4; ++fm)
        #pragma unroll
        for (int fn = 0; fn < 4; ++fn)
            #pragma unroll
            for (int reg = 0; reg < 4; ++reg) {
                int row = wr * 64 + fm * 16 + (lane >> 4) * 4 + reg;
                int col = wc * 64 + fn * 16 + (lane & 15);
                Cp[row * 128 + col] = acc[fm][fn][reg];
            }
}

// ------- Kernel 5: masked squared-diff reduction -> loss -------
__global__ void reduce_loss(const float* __restrict__ Cpart, float* __restrict__ out) {
    int tile = blockIdx.x;
    int r = 0, t = tile;
    while (t >= 8 - r) { t -= 8 - r; ++r; }
    int c = r + t;
    const float* x0 = Cpart + (size_t)(0 * 36 + tile) * 16384;
    const float* x1 = Cpart + (size_t)(1 * 36 + tile) * 16384;
    const float* y0 = Cpart + (size_t)(2 * 36 + tile) * 16384;
    const float* y1 = Cpart + (size_t)(3 * 36 + tile) * 16384;
    const float inv_n = 1.0f / (float)NROWS;
    float s = 0.f;
    for (int e = threadIdx.x; e < 16384; e += 256) {
        int row = e >> 7, col = e & 127;
        if (r == c && col <= row) continue;
        float d = ((x0[e] + x1[e]) - (y0[e] + y1[e])) * inv_n;
        s += d * d;
    }
    #pragma unroll
    for (int off = 32; off > 0; off >>= 1) s += __shfl_down(s, off, 64);
    __shared__ float wsum[4];
    int lane = threadIdx.x & 63, wid = threadIdx.x >> 6;
    if (lane == 0) wsum[wid] = s;
    __syncthreads();
    if (threadIdx.x == 0) {
        float tot = wsum[0] + wsum[1] + wsum[2] + wsum[3];
        atomicAdd(out, tot * (1.0f / 523776.0f));
    }
}

extern "C" void kernel_launch(void* const* d_in, const int* in_sizes, int n_in,
                              void* d_out, int out_size, void* d_ws, size_t ws_size,
                              hipStream_t stream) {
    const float* X = (const float*)d_in[0];
    const float* Y = (const float*)d_in[1];
    char* ws = (char*)d_ws;
    // layout (bytes):
    //   0        Xst  bf16 [1024][8192]  16 MB
    //   16 MB    Yst  bf16 [1024][8192]  16 MB
    //   32 MB    Cpart f32 [2 mat][2 split][36 tiles][128][128]  9.44 MB
    //   42991616 psum  f32 [2][64][1024]  512 KB
    //   43515904 psq   f32 [2][64][1024]  512 KB
    //   44040192 mu    f32 [2][1024]      8 KB
    //   44048384 isd   f32 [2][1024]      8 KB
    __hip_bfloat16* Xst = (__hip_bfloat16*)(ws);
    __hip_bfloat16* Yst = (__hip_bfloat16*)(ws + (16u << 20));
    float* Cpart = (float*)(ws + (32u << 20));
    float* psum  = (float*)(ws + 42991616u);
    float* psq   = (float*)(ws + 43515904u);
    float* mu    = (float*)(ws + 44040192u);
    float* isd   = (float*)(ws + 44048384u);
    float* out   = (float*)d_out;

    hipMemsetAsync(out, 0, sizeof(float), stream);
    stats_partial<<<dim3(4, 64, 2), 256, 0, stream>>>(X, Y, psum, psq);
    stats_final<<<8, 256, 0, stream>>>(psum, psq, mu, isd);
    std_transpose<<<dim3(16, 128, 2), 256, 0, stream>>>(X, Y, mu, isd, Xst, Yst);
    gram_gemm<<<dim3(36, 2, 2), 256, 0, stream>>>(Xst, Yst, Cpart);
    reduce_loss<<<36, 256, 0, stream>>>(Cpart, out);
}

// Round 7
// 179.217 us; speedup vs baseline: 1.2725x; 1.2725x over previous
//
#include <hip/hip_runtime.h>
#include <hip/hip_bf16.h>
#include <stdint.h>

#define NROWS 8192
#define NF    1024
#define EPSV  1e-5f

typedef __attribute__((ext_vector_type(8))) short bf16x8;
typedef __attribute__((ext_vector_type(4))) float f32x4;

static __device__ __forceinline__ unsigned short f2bf(float v) {
    __hip_bfloat16 b = __float2bfloat16(v);
    return *reinterpret_cast<unsigned short*>(&b);
}

// ---------------- Kernel 1: per-chunk column sums ----------------
__global__ void stats_partial(const float* __restrict__ X, const float* __restrict__ Y,
                              float* __restrict__ psum, float* __restrict__ psq) {
    int cg    = blockIdx.x;   // 0..3  column group of 256
    int chunk = blockIdx.y;   // 0..63 row chunk of 128
    int mat   = blockIdx.z;   // 0..1
    const float* A = mat ? Y : X;
    int col = cg * 256 + threadIdx.x;
    const float* p = A + (size_t)(chunk * 128) * NF + col;
    float s = 0.f, sq = 0.f;
    #pragma unroll 4
    for (int i = 0; i < 128; ++i) {
        float v = p[(size_t)i * NF];
        s += v; sq += v * v;
    }
    int idx = (mat * 64 + chunk) * NF + col;
    psum[idx] = s;
    psq[idx]  = sq;
}

// ---------------- Kernel 2: finalize mu / inv_sd (32 blocks) ----------------
__global__ void stats_final(const float* __restrict__ psum, const float* __restrict__ psq,
                            float* __restrict__ mu, float* __restrict__ isd) {
    __shared__ float ls[4][64], lq[4][64];
    int mat  = blockIdx.y;
    int col0 = blockIdx.x * 64;          // 16 x-blocks
    int colq = threadIdx.x & 63;
    int g    = threadIdx.x >> 6;         // 4 chunk groups of 16
    int col  = col0 + colq;
    float s = 0.f, sq = 0.f;
    #pragma unroll
    for (int k = 0; k < 16; ++k) {
        int idx = (mat * 64 + g * 16 + k) * NF + col;
        s  += psum[idx];
        sq += psq[idx];
    }
    ls[g][colq] = s; lq[g][colq] = sq;
    __syncthreads();
    if (g == 0) {
        s  = ls[0][colq] + ls[1][colq] + ls[2][colq] + ls[3][colq];
        sq = lq[0][colq] + lq[1][colq] + lq[2][colq] + lq[3][colq];
        float m   = s / (float)NROWS;
        float var = (sq - s * m) / (float)(NROWS - 1);
        var = fmaxf(var, 0.f);
        mu [mat * NF + col] = m;
        isd[mat * NF + col] = 1.0f / (sqrtf(var) + EPSV);
    }
}

// ------- Kernel 3: standardize + bf16 cast + transpose to [col][k] -------
__global__ void std_transpose(const float* __restrict__ X, const float* __restrict__ Y,
                              const float* __restrict__ mu, const float* __restrict__ isd,
                              unsigned short* __restrict__ Xst, unsigned short* __restrict__ Yst) {
    __shared__ unsigned short sbuf[64][68];
    __shared__ float smu[64], sisd[64];
    int ct  = blockIdx.x;    // 0..15  column tile
    int rt  = blockIdx.y;    // 0..127 row tile
    int mat = blockIdx.z;
    const float* A = mat ? Y : X;
    unsigned short* O = mat ? Yst : Xst;
    int tid = threadIdx.x;
    if (tid < 64) {
        smu[tid]  = mu [mat * NF + ct * 64 + tid];
        sisd[tid] = isd[mat * NF + ct * 64 + tid];
    }
    __syncthreads();
    #pragma unroll
    for (int it = 0; it < 4; ++it) {
        int idx = it * 256 + tid;     // 0..1023
        int row = idx >> 4;           // 0..63
        int c4  = idx & 15;           // 0..15
        float4 v = *reinterpret_cast<const float4*>(
            A + (size_t)(rt * 64 + row) * NF + ct * 64 + c4 * 4);
        ushort4 o;
        o.x = f2bf((v.x - smu[c4 * 4 + 0]) * sisd[c4 * 4 + 0]);
        o.y = f2bf((v.y - smu[c4 * 4 + 1]) * sisd[c4 * 4 + 1]);
        o.z = f2bf((v.z - smu[c4 * 4 + 2]) * sisd[c4 * 4 + 2]);
        o.w = f2bf((v.w - smu[c4 * 4 + 3]) * sisd[c4 * 4 + 3]);
        *reinterpret_cast<ushort4*>(&sbuf[row][c4 * 4]) = o;
    }
    __syncthreads();
    {
        int c  = tid >> 2;            // 0..63 output column
        int r8 = tid & 3;             // 16-row group
        bf16x8 v0, v1;
        #pragma unroll
        for (int i = 0; i < 8; ++i) v0[i] = (short)sbuf[r8 * 16 + i][c];
        #pragma unroll
        for (int i = 0; i < 8; ++i) v1[i] = (short)sbuf[r8 * 16 + 8 + i][c];
        unsigned short* dst = O + (size_t)(ct * 64 + c) * NROWS + rt * 64 + r8 * 16;
        *reinterpret_cast<bf16x8*>(dst)     = v0;
        *reinterpret_cast<bf16x8*>(dst + 8) = v1;
    }
}

// ------- Kernel 4: Gram GEMM, 128x128 tile, BK=64, XOR-swizzled LDS -------
__global__ __launch_bounds__(256, 2) void gram_gemm(
    const unsigned short* __restrict__ Xst, const unsigned short* __restrict__ Yst,
    float* __restrict__ Cpart, int nsplit, int kper) {
    __shared__ short As[128 * 64];   // 128 rows x 128B, k-slot XOR-swizzled
    __shared__ short Bs[128 * 64];
    int tile = blockIdx.x, split = blockIdx.y, mat = blockIdx.z;
    int r = 0, t = tile;
    while (t >= 8 - r) { t -= 8 - r; ++r; }
    int c = r + t;
    const short* A = reinterpret_cast<const short*>(mat ? Yst : Xst);
    int tid = threadIdx.x, lane = tid & 63, wid = tid >> 6;
    int wr = wid >> 1, wc = wid & 1;
    f32x4 acc[4][4] = {};
    int k0 = split * kper;
    int nstep = kper >> 6;
    int r_loc = lane >> 3;                 // 0..7
    int kc    = (lane & 7) ^ r_loc;        // swizzled source 16B block

    for (int step = 0; step < nstep; ++step) {
        int kk = k0 + step * 64;
        __syncthreads();   // previous tile consumed
        #pragma unroll
        for (int i = 0; i < 4; ++i) {
            int chunk = wid * 4 + i;       // 0..15, 8 rows each
            int row = chunk * 8 + r_loc;
            const short* ga = A + (size_t)(r * 128 + row) * NROWS + kk + kc * 8;
            __builtin_amdgcn_global_load_lds(
                (const __attribute__((address_space(1))) void*)ga,
                (__attribute__((address_space(3))) void*)(As + chunk * 512), 16, 0, 0);
            const short* gb = A + (size_t)(c * 128 + row) * NROWS + kk + kc * 8;
            __builtin_amdgcn_global_load_lds(
                (const __attribute__((address_space(1))) void*)gb,
                (__attribute__((address_space(3))) void*)(Bs + chunk * 512), 16, 0, 0);
        }
        __syncthreads();   // loads complete
        bf16x8 af[4][2], bfr[4][2];
        #pragma unroll
        for (int fm = 0; fm < 4; ++fm) {
            int rowA = wr * 64 + fm * 16 + (lane & 15);
            int rowB = wc * 64 + fm * 16 + (lane & 15);
            #pragma unroll
            for (int h = 0; h < 2; ++h) {
                int kb = h * 4 + (lane >> 4);
                af [fm][h] = *reinterpret_cast<const bf16x8*>(
                    As + rowA * 64 + ((kb ^ (rowA & 7)) * 8));
                bfr[fm][h] = *reinterpret_cast<const bf16x8*>(
                    Bs + rowB * 64 + ((kb ^ (rowB & 7)) * 8));
            }
        }
        #pragma unroll
        for (int h = 0; h < 2; ++h)
            #pragma unroll
            for (int fm = 0; fm < 4; ++fm)
                #pragma unroll
                for (int fn = 0; fn < 4; ++fn)
                    acc[fm][fn] = __builtin_amdgcn_mfma_f32_16x16x32_bf16(
                        af[fm][h], bfr[fn][h], acc[fm][fn], 0, 0, 0);
    }

    float* Cp = Cpart + ((size_t)(mat * nsplit + split) * 36 + tile) * 16384;
    #pragma unroll
    for (int fm = 0; fm < 4; ++fm)
        #pragma unroll
        for (int fn = 0; fn < 4; ++fn)
            #pragma unroll
            for (int reg = 0; reg < 4; ++reg) {
                int row = wr * 64 + fm * 16 + (lane >> 4) * 4 + reg;
                int col = wc * 64 + fn * 16 + (lane & 15);
                Cp[row * 128 + col] = acc[fm][fn][reg];
            }
}

// ------- Kernel 5: masked squared-diff reduction -> loss -------
__global__ void reduce_loss(const float* __restrict__ Cpart, float* __restrict__ out,
                            int nsplit) {
    int tile = blockIdx.x, sub = blockIdx.y;   // sub: 16-row band
    int r = 0, t = tile;
    while (t >= 8 - r) { t -= 8 - r; ++r; }
    int c = r + t;
    const float inv_n = 1.0f / (float)NROWS;
    float s = 0.f;
    for (int e4 = threadIdx.x; e4 < 512; e4 += 256) {   // float4 units
        int row  = sub * 16 + (e4 >> 5);
        int col0 = (e4 & 31) * 4;
        float xs0 = 0.f, xs1 = 0.f, xs2 = 0.f, xs3 = 0.f;
        float ys0 = 0.f, ys1 = 0.f, ys2 = 0.f, ys3 = 0.f;
        for (int sp = 0; sp < nsplit; ++sp) {
            float4 vx = *reinterpret_cast<const float4*>(
                Cpart + ((size_t)sp * 36 + tile) * 16384 + row * 128 + col0);
            float4 vy = *reinterpret_cast<const float4*>(
                Cpart + ((size_t)(nsplit + sp) * 36 + tile) * 16384 + row * 128 + col0);
            xs0 += vx.x; xs1 += vx.y; xs2 += vx.z; xs3 += vx.w;
            ys0 += vy.x; ys1 += vy.y; ys2 += vy.z; ys3 += vy.w;
        }
        float dv[4] = {xs0 - ys0, xs1 - ys1, xs2 - ys2, xs3 - ys3};
        #pragma unroll
        for (int j = 0; j < 4; ++j) {
            int col = col0 + j;
            if (r == c && col <= row) continue;
            float d = dv[j] * inv_n;
            s += d * d;
        }
    }
    #pragma unroll
    for (int off = 32; off > 0; off >>= 1) s += __shfl_down(s, off, 64);
    __shared__ float wsum[4];
    int lane = threadIdx.x & 63, wid = threadIdx.x >> 6;
    if (lane == 0) wsum[wid] = s;
    __syncthreads();
    if (threadIdx.x == 0) {
        float tot = wsum[0] + wsum[1] + wsum[2] + wsum[3];
        atomicAdd(out, tot * (1.0f / 523776.0f));
    }
}

extern "C" void kernel_launch(void* const* d_in, const int* in_sizes, int n_in,
                              void* d_out, int out_size, void* d_ws, size_t ws_size,
                              hipStream_t stream) {
    const float* X = (const float*)d_in[0];
    const float* Y = (const float*)d_in[1];
    char* ws = (char*)d_ws;

    // pick largest split-K that fits the workspace
    auto need = [](int ns) -> size_t {
        return ((size_t)32 << 20)                       // Xst + Yst
             + (size_t)2 * ns * 36 * 16384 * 4          // Cpart
             + ((size_t)512 << 10) * 2                  // psum + psq
             + ((size_t)8 << 10) * 2;                   // mu + isd
    };
    int nsplit = 8;
    if (ws_size < need(8)) nsplit = 4;
    if (ws_size < need(4)) nsplit = 2;
    if (ws_size < need(2)) nsplit = 1;
    int kper = NROWS / nsplit;

    unsigned short* Xst = (unsigned short*)(ws);
    unsigned short* Yst = (unsigned short*)(ws + ((size_t)16 << 20));
    float* Cpart = (float*)(ws + ((size_t)32 << 20));
    size_t cpart_sz = (size_t)2 * nsplit * 36 * 16384 * 4;
    float* psum = (float*)(ws + ((size_t)32 << 20) + cpart_sz);
    float* psq  = psum + 2 * 64 * NF;
    float* mu   = psq  + 2 * 64 * NF;
    float* isd  = mu   + 2 * NF;
    float* out  = (float*)d_out;

    hipMemsetAsync(out, 0, sizeof(float), stream);
    stats_partial<<<dim3(4, 64, 2), 256, 0, stream>>>(X, Y, psum, psq);
    stats_final<<<dim3(16, 2), 256, 0, stream>>>(psum, psq, mu, isd);
    std_transpose<<<dim3(16, 128, 2), 256, 0, stream>>>(X, Y, mu, isd, Xst, Yst);
    gram_gemm<<<dim3(36, nsplit, 2), 256, 0, stream>>>(Xst, Yst, Cpart, nsplit, kper);
    reduce_loss<<<dim3(36, 8), 256, 0, stream>>>(Cpart, out, nsplit);
}

// Round 8
// 161.061 us; speedup vs baseline: 1.4159x; 1.1127x over previous
//
#include <hip/hip_runtime.h>
#include <hip/hip_bf16.h>
#include <stdint.h>

#define NROWS 8192
#define NF    1024
#define EPSV  1e-5f

typedef __attribute__((ext_vector_type(8))) short bf16x8;
typedef __attribute__((ext_vector_type(4))) float f32x4;

static __device__ __forceinline__ unsigned short f2bf(float v) {
    __hip_bfloat16 b = __float2bfloat16(v);
    return *reinterpret_cast<unsigned short*>(&b);
}
static __device__ __forceinline__ float bf2f(unsigned short u) {
    union { uint32_t i; float f; } cv; cv.i = (uint32_t)u << 16; return cv.f;
}

// ---- Kernel 1: transpose raw->bf16 [col][k] + per-block column stats ----
// Phase A: coalesced f32 reads, cast, conflict-free b64 LDS writes (68-pad).
// Phase B: column gathers -> bf16x8 global writes + f32 sum/sumsq partials.
__global__ void transpose_stats(const float* __restrict__ X, const float* __restrict__ Y,
                                unsigned short* __restrict__ Xst, unsigned short* __restrict__ Yst,
                                float* __restrict__ psum, float* __restrict__ psq) {
    __shared__ unsigned short sbuf[64][68];
    int ct  = blockIdx.x;    // 0..15  column tile
    int rt  = blockIdx.y;    // 0..127 row tile (64 rows each)
    int mat = blockIdx.z;
    const float* A = mat ? Y : X;
    unsigned short* O = mat ? Yst : Xst;
    int tid = threadIdx.x;
    #pragma unroll
    for (int it = 0; it < 4; ++it) {
        int idx = it * 256 + tid;     // 0..1023
        int row = idx >> 4;           // 0..63
        int c4  = idx & 15;           // 0..15
        float4 v = *reinterpret_cast<const float4*>(
            A + (size_t)(rt * 64 + row) * NF + ct * 64 + c4 * 4);
        ushort4 o;
        o.x = f2bf(v.x); o.y = f2bf(v.y); o.z = f2bf(v.z); o.w = f2bf(v.w);
        *reinterpret_cast<ushort4*>(&sbuf[row][c4 * 4]) = o;
    }
    __syncthreads();
    {
        int c  = tid >> 2;            // 0..63 output column
        int r8 = tid & 3;             // 16-row group
        bf16x8 v0, v1;
        float s = 0.f, sq = 0.f;
        #pragma unroll
        for (int i = 0; i < 8; ++i) {
            unsigned short u = sbuf[r8 * 16 + i][c];
            v0[i] = (short)u;
            float f = bf2f(u); s += f; sq += f * f;
        }
        #pragma unroll
        for (int i = 0; i < 8; ++i) {
            unsigned short u = sbuf[r8 * 16 + 8 + i][c];
            v1[i] = (short)u;
            float f = bf2f(u); s += f; sq += f * f;
        }
        unsigned short* dst = O + (size_t)(ct * 64 + c) * NROWS + rt * 64 + r8 * 16;
        *reinterpret_cast<bf16x8*>(dst)     = v0;
        *reinterpret_cast<bf16x8*>(dst + 8) = v1;
        s  += __shfl_xor(s, 1);  s  += __shfl_xor(s, 2);
        sq += __shfl_xor(sq, 1); sq += __shfl_xor(sq, 2);
        if (r8 == 0) {
            int pidx = (mat * 128 + rt) * NF + ct * 64 + c;
            psum[pidx] = s;
            psq[pidx]  = sq;
        }
    }
}

// ---------------- Kernel 2: finalize mu / inv_sd ----------------
__global__ void stats_final(const float* __restrict__ psum, const float* __restrict__ psq,
                            float* __restrict__ mu, float* __restrict__ isd) {
    __shared__ float ls[4][64], lq[4][64];
    int mat  = blockIdx.y;
    int col0 = blockIdx.x * 64;          // 16 x-blocks
    int colq = threadIdx.x & 63;
    int g    = threadIdx.x >> 6;         // 4 groups of 32 chunks
    int col  = col0 + colq;
    float s = 0.f, sq = 0.f;
    #pragma unroll
    for (int k = 0; k < 32; ++k) {
        int idx = (mat * 128 + g * 32 + k) * NF + col;
        s  += psum[idx];
        sq += psq[idx];
    }
    ls[g][colq] = s; lq[g][colq] = sq;
    __syncthreads();
    if (g == 0) {
        s  = ls[0][colq] + ls[1][colq] + ls[2][colq] + ls[3][colq];
        sq = lq[0][colq] + lq[1][colq] + lq[2][colq] + lq[3][colq];
        float m   = s / (float)NROWS;
        float var = (sq - s * m) / (float)(NROWS - 1);
        var = fmaxf(var, 0.f);
        mu [mat * NF + col] = m;
        isd[mat * NF + col] = 1.0f / (sqrtf(var) + EPSV);
    }
}

// ---- Kernel 3: fused X/Y Gram GEMM, BK=32 dbuf pipeline, vmcnt(8) ----
// corr = isd*(G - n*mu*mu^T)*isd / n applied in epilogue; writes X-Y diff.
__global__ __launch_bounds__(256, 2) void gram_fused(
    const unsigned short* __restrict__ Xst, const unsigned short* __restrict__ Yst,
    const float* __restrict__ mu, const float* __restrict__ isd,
    float* __restrict__ Cdiff, int nsplit, int kper) {
    // 8 buffers of 128x32 bf16 (8KB): [0/1]=X-A dbuf, [2/3]=X-B, [4/5]=Y-A, [6/7]=Y-B
    __shared__ short lds[8][128 * 32];
    int nwg = 36 * nsplit, cpx = nwg >> 3;
    int bid = blockIdx.x;
    int swz = (bid & 7) * cpx + (bid >> 3);   // XCD-chunked (nwg % 8 == 0)
    int split = swz / 36, tile = swz % 36;
    int r = 0, t0 = tile;
    while (t0 >= 8 - r) { t0 -= 8 - r; ++r; }
    int c = r + t0;
    const short* Xs = reinterpret_cast<const short*>(Xst);
    const short* Ys = reinterpret_cast<const short*>(Yst);
    int tid = threadIdx.x, lane = tid & 63, wid = tid >> 6;
    int wr = wid >> 1, wc = wid & 1;
    f32x4 accX[4][4] = {}, accY[4][4] = {};
    int k0 = split * kper;
    int nstep = kper >> 5;                    // power of two
    // staging: lane covers (row rw, phys slot lane&3); source slot pre-permuted
    // by the inverse of the read swizzle: s = (phys - (row>>1)) & 3
    int s8 = ((lane & 3) - (lane >> 3)) & 3;

    auto stage = [&](const short* M, short* bA, short* bB, int ts) {
        int kk = k0 + ts * 32;
        #pragma unroll
        for (int i = 0; i < 2; ++i) {
            int chunk = wid * 2 + i;              // 0..7, 16 rows each
            int rw = chunk * 16 + (lane >> 2);
            size_t ko = (size_t)kk + s8 * 8;
            const short* ga = M + (size_t)(r * 128 + rw) * NROWS + ko;
            __builtin_amdgcn_global_load_lds(
                (const __attribute__((address_space(1))) void*)ga,
                (__attribute__((address_space(3))) void*)(bA + chunk * 512), 16, 0, 0);
            const short* gb = M + (size_t)(c * 128 + rw) * NROWS + ko;
            __builtin_amdgcn_global_load_lds(
                (const __attribute__((address_space(1))) void*)gb,
                (__attribute__((address_space(3))) void*)(bB + chunk * 512), 16, 0, 0);
        }
    };
    auto compute = [&](const short* bA, const short* bB, f32x4 (&acc)[4][4]) {
        bf16x8 a[4], b[4];
        int rl = lane & 15;
        int sl = ((lane >> 4) + (rl >> 1)) & 3;   // read-side swizzle
        #pragma unroll
        for (int f = 0; f < 4; ++f) {
            a[f] = *reinterpret_cast<const bf16x8*>(bA + (wr * 64 + f * 16 + rl) * 32 + sl * 8);
            b[f] = *reinterpret_cast<const bf16x8*>(bB + (wc * 64 + f * 16 + rl) * 32 + sl * 8);
        }
        #pragma unroll
        for (int fm = 0; fm < 4; ++fm)
            #pragma unroll
            for (int fn = 0; fn < 4; ++fn)
                acc[fm][fn] = __builtin_amdgcn_mfma_f32_16x16x32_bf16(
                    a[fm], b[fn], acc[fm][fn], 0, 0, 0);
    };

    stage(Xs, lds[0], lds[2], 0);
    stage(Ys, lds[4], lds[6], 0);
    for (int t = 0; t < nstep; ++t) {
        int cur = t & 1, nxt = cur ^ 1;
        int tn = (t + 1) & (nstep - 1);           // dummy re-stage on last iter
        stage(Xs, lds[0 + nxt], lds[2 + nxt], tn);
        asm volatile("s_waitcnt vmcnt(8)" ::: "memory");   // X(t) landed
        __builtin_amdgcn_s_barrier();
        __builtin_amdgcn_sched_barrier(0);
        compute(lds[0 + cur], lds[2 + cur], accX);
        stage(Ys, lds[4 + nxt], lds[6 + nxt], tn);
        asm volatile("s_waitcnt vmcnt(8)" ::: "memory");   // Y(t) landed
        __builtin_amdgcn_s_barrier();
        __builtin_amdgcn_sched_barrier(0);
        compute(lds[4 + cur], lds[6 + cur], accY);
    }
    asm volatile("s_waitcnt vmcnt(0)" ::: "memory");       // drain dummy stages

    // epilogue: corrX - corrY partial for this split
    const float* mux = mu;        const float* muy = mu  + NF;
    const float* isx = isd;       const float* isy = isd + NF;
    const float inv_n = 1.0f / (float)NROWS;
    float f0 = (split == 0) ? 1.0f : 0.0f;      // const term applied once
    float mxc[4], ixc[4], myc[4], iyc[4];
    #pragma unroll
    for (int fn = 0; fn < 4; ++fn) {
        int cf = c * 128 + wc * 64 + fn * 16 + (lane & 15);
        mxc[fn] = mux[cf]; ixc[fn] = isx[cf];
        myc[fn] = muy[cf]; iyc[fn] = isy[cf];
    }
    float* Cp = Cdiff + ((size_t)split * 36 + tile) * 16384;
    #pragma unroll
    for (int fm = 0; fm < 4; ++fm)
        #pragma unroll
        for (int reg = 0; reg < 4; ++reg) {
            int rf = r * 128 + wr * 64 + fm * 16 + (lane >> 4) * 4 + reg;
            float mxr = mux[rf], ixr = isx[rf];
            float myr = muy[rf], iyr = isy[rf];
            int rowl = wr * 64 + fm * 16 + (lane >> 4) * 4 + reg;
            #pragma unroll
            for (int fn = 0; fn < 4; ++fn) {
                float cx = (accX[fm][fn][reg] * inv_n - f0 * mxr * mxc[fn]) * ixr * ixc[fn];
                float cy = (accY[fm][fn][reg] * inv_n - f0 * myr * myc[fn]) * iyr * iyc[fn];
                int coll = wc * 64 + fn * 16 + (lane & 15);
                Cp[rowl * 128 + coll] = cx - cy;
            }
        }
}

// ------- Kernel 4: masked squared-diff reduction -> loss -------
__global__ void reduce_loss(const float* __restrict__ Cdiff, float* __restrict__ out,
                            int nsplit) {
    int tile = blockIdx.x, sub = blockIdx.y;   // sub: 16-row band
    int r = 0, t = tile;
    while (t >= 8 - r) { t -= 8 - r; ++r; }
    int c = r + t;
    float s = 0.f;
    for (int e4 = threadIdx.x; e4 < 512; e4 += 256) {   // float4 units
        int row  = sub * 16 + (e4 >> 5);
        int col0 = (e4 & 31) * 4;
        float d0 = 0.f, d1 = 0.f, d2 = 0.f, d3 = 0.f;
        for (int sp = 0; sp < nsplit; ++sp) {
            float4 v = *reinterpret_cast<const float4*>(
                Cdiff + ((size_t)sp * 36 + tile) * 16384 + row * 128 + col0);
            d0 += v.x; d1 += v.y; d2 += v.z; d3 += v.w;
        }
        float dv[4] = {d0, d1, d2, d3};
        #pragma unroll
        for (int j = 0; j < 4; ++j) {
            int col = col0 + j;
            if (r == c && col <= row) continue;
            s += dv[j] * dv[j];
        }
    }
    #pragma unroll
    for (int off = 32; off > 0; off >>= 1) s += __shfl_down(s, off, 64);
    __shared__ float wsum[4];
    int lane = threadIdx.x & 63, wid = threadIdx.x >> 6;
    if (lane == 0) wsum[wid] = s;
    __syncthreads();
    if (threadIdx.x == 0) {
        float tot = wsum[0] + wsum[1] + wsum[2] + wsum[3];
        atomicAdd(out, tot * (1.0f / 523776.0f));
    }
}

extern "C" void kernel_launch(void* const* d_in, const int* in_sizes, int n_in,
                              void* d_out, int out_size, void* d_ws, size_t ws_size,
                              hipStream_t stream) {
    const float* X = (const float*)d_in[0];
    const float* Y = (const float*)d_in[1];
    char* ws = (char*)d_ws;

    // pick largest split-K that fits the workspace
    auto need = [](int ns) -> size_t {
        return ((size_t)32 << 20)                       // Xst + Yst
             + (size_t)ns * 36 * 16384 * 4              // Cdiff
             + (size_t)2 * 128 * NF * 4 * 2             // psum + psq (2 MB)
             + (size_t)2 * NF * 4 * 2;                  // mu + isd
    };
    int nsplit = 16;
    if (ws_size < need(16)) nsplit = 8;
    if (ws_size < need(8))  nsplit = 4;
    int kper = NROWS / nsplit;

    unsigned short* Xst = (unsigned short*)(ws);
    unsigned short* Yst = (unsigned short*)(ws + ((size_t)16 << 20));
    float* Cdiff = (float*)(ws + ((size_t)32 << 20));
    size_t cd_sz = (size_t)nsplit * 36 * 16384 * 4;
    float* psum = (float*)(ws + ((size_t)32 << 20) + cd_sz);
    float* psq  = psum + 2 * 128 * NF;
    float* mu   = psq  + 2 * 128 * NF;
    float* isd  = mu   + 2 * NF;
    float* out  = (float*)d_out;

    hipMemsetAsync(out, 0, sizeof(float), stream);
    transpose_stats<<<dim3(16, 128, 2), 256, 0, stream>>>(X, Y, Xst, Yst, psum, psq);
    stats_final<<<dim3(16, 2), 256, 0, stream>>>(psum, psq, mu, isd);
    gram_fused<<<36 * nsplit, 256, 0, stream>>>(Xst, Yst, mu, isd, Cdiff, nsplit, kper);
    reduce_loss<<<dim3(36, 8), 256, 0, stream>>>(Cdiff, out, nsplit);
}